// Round 21
// baseline (168.270 us; speedup 1.0000x reference)
//
#include <hip/hip_runtime.h>
#include <stdint.h>

#define BATCH 4
#define CH 64
#define HW 80
#define NPIX 6400
#define SPLITS 3

typedef __attribute__((ext_vector_type(8))) short bf16x8;
typedef __attribute__((ext_vector_type(4))) float f32x4;

#define QSCALE 1.2011224087864498f   // sqrt(log2(e))
#define ESHIFT 115.41560327111707f   // 80 * log2(e)

static __device__ __forceinline__ unsigned short f2bf(float f) {
  union { float f; unsigned int u; } v; v.f = f;
  unsigned int u = v.u;
  return (unsigned short)((u + 0x7fffu + ((u >> 16) & 1u)) >> 16);
}
static __device__ __forceinline__ float bf2f(unsigned short h) {
  union { unsigned int u; float f; } v; v.u = ((unsigned int)h) << 16;
  return v.f;
}
// fp32 -> (hi bf16 | lo bf16 << 16)
static __device__ __forceinline__ unsigned int split_pack(float a) {
  unsigned short hi = f2bf(a);
  union { unsigned int u; float f; } hf; hf.u = ((unsigned int)hi) << 16;
  unsigned short lo = f2bf(a - hf.f);
  return (unsigned int)hi | ((unsigned int)lo << 16);
}
// de-interleave 8 split-packed uints (2x uint4) into hi/lo bf16x8 fragments
static __device__ __forceinline__ void deint(uint4 a, uint4 b, bf16x8* h, bf16x8* l) {
  union { unsigned int u[4]; bf16x8 v; } H, L;
  H.u[0] = __builtin_amdgcn_perm(a.y, a.x, 0x05040100u);
  H.u[1] = __builtin_amdgcn_perm(a.w, a.z, 0x05040100u);
  H.u[2] = __builtin_amdgcn_perm(b.y, b.x, 0x05040100u);
  H.u[3] = __builtin_amdgcn_perm(b.w, b.z, 0x05040100u);
  L.u[0] = __builtin_amdgcn_perm(a.y, a.x, 0x07060302u);
  L.u[1] = __builtin_amdgcn_perm(a.w, a.z, 0x07060302u);
  L.u[2] = __builtin_amdgcn_perm(b.y, b.x, 0x07060302u);
  L.u[3] = __builtin_amdgcn_perm(b.w, b.z, 0x07060302u);
  *h = H.v; *l = L.v;
}

// ---------------- QKV 1x1 conv ----------------
// v21: output-split 400 -> 800 blocks. half 0: o in [0,96) (owns all Q
// channels -> fills qs + does Q restage); half 1: o in [96,192). Per-thread
// serial FMAs halve (1536 -> 768); waves/SIMD double (3.1 -> 6.25). Same
// per-output c-loop order -> bit-identical outputs.
__global__ __launch_bounds__(512) void qkv_kernel(
    const float* __restrict__ x, const float* __restrict__ w,
    const float* __restrict__ bias, unsigned short* __restrict__ Qtbf,
    unsigned short* __restrict__ Vbf, unsigned int* __restrict__ Kpk,
    unsigned int* __restrict__ Qtn) {
  __shared__ float xs[64][65];  // [channel][pixel]
  __shared__ float qs[64][65];
  int bid = blockIdx.x;
  int b = bid / 200;
  int rem = bid % 200;
  int tile = rem >> 1, half = rem & 1;
  int p0 = tile * 64;
  int t = threadIdx.x;
  int i = t & 63;
  int og = __builtin_amdgcn_readfirstlane(t >> 6);  // 0..7
  int p = p0 + i;
  int tp = (p % HW) * HW + p / HW;  // involution transpose
  size_t bc = (size_t)b * CH * NPIX;
  // stage x[b][:, p0..p0+64) -> xs (coalesced: 8 threads/row x 8 floats)
  {
    int cr = t >> 3;         // channel 0..63
    int j0 = (t & 7) * 8;    // pixel chunk 0,8,..,56
    const float* xrow = x + bc + (size_t)cr * NPIX + p0 + j0;
    float4 xa = *(const float4*)&xrow[0];
    float4 xb4 = *(const float4*)&xrow[4];
    xs[cr][j0 + 0] = xa.x; xs[cr][j0 + 1] = xa.y;
    xs[cr][j0 + 2] = xa.z; xs[cr][j0 + 3] = xa.w;
    xs[cr][j0 + 4] = xb4.x; xs[cr][j0 + 5] = xb4.y;
    xs[cr][j0 + 6] = xb4.z; xs[cr][j0 + 7] = xb4.w;
  }
  __syncthreads();
  float xv[64];
#pragma unroll
  for (int c = 0; c < 64; ++c) xv[c] = xs[c][i];
  int obase = half * 96 + og * 12;
  for (int j = 0; j < 12; j += 4) {
    int o = obase + j;
    const float* wr0 = w + o * 64;
    const float* wr1 = wr0 + 64;
    const float* wr2 = wr0 + 128;
    const float* wr3 = wr0 + 192;
    float a0 = bias[o], a1 = bias[o + 1], a2 = bias[o + 2], a3 = bias[o + 3];
#pragma unroll
    for (int c = 0; c < 64; ++c) {
      float xc = xv[c];
      a0 += wr0[c] * xc;
      a1 += wr1[c] * xc;
      a2 += wr2[c] * xc;
      a3 += wr3[c] * xc;
    }
    float av[4] = {a0, a1, a2, a3};
#pragma unroll
    for (int u = 0; u < 4; ++u) {
      int oo = o + u;
      int cc = oo & 63;
      int kind = oo >> 6;
      float a = av[u];
      if (kind == 0) {
        qs[cc][i] = a;
        Qtn[bc + (size_t)cc * NPIX + tp] = split_pack(a);
      } else if (kind == 1) {
        Kpk[bc + (size_t)cc * NPIX + p] = split_pack(a);
      } else {
        Vbf[bc + (size_t)cc * NPIX + p] = f2bf(a);
      }
    }
  }
  if (half == 0) {
    __syncthreads();
    // restage q -> Qtbf rows (row 128B contiguous, scaled by QSCALE);
    // qs fully populated by this block (o in [0,96) covers all Q channels)
    int j2 = t >> 3, g = t & 7;  // j2 in [0,64), g in [0,8)
    int pj = p0 + j2;
    int tpj = (pj % HW) * HW + pj / HW;
    unsigned int pk4[4];
#pragma unroll
    for (int q4 = 0; q4 < 4; ++q4) {
      float a0 = qs[g * 8 + q4 * 2][j2] * QSCALE;
      float a1 = qs[g * 8 + q4 * 2 + 1][j2] * QSCALE;
      pk4[q4] = (unsigned int)f2bf(a0) | ((unsigned int)f2bf(a1) << 16);
    }
    unsigned short* dst = Qtbf + ((size_t)b * NPIX + tpj) * 64 + g * 8;
    uint4 w0 = {pk4[0], pk4[1], pk4[2], pk4[3]};
    *(uint4*)&dst[0] = w0;
  }
}

// ---------------- fused flash + gram ----------------
// v19-proven: blocks 0-1199 = flash (R11 body), 1200-1599 = gram (R4 body).
__global__ __launch_bounds__(256, 4) void flashgram_kernel(
    const unsigned short* __restrict__ Qtbf, const unsigned short* __restrict__ Vbf,
    float* __restrict__ Opart, float* __restrict__ Lpart,
    const unsigned int* __restrict__ Kpk, const unsigned int* __restrict__ Qtn,
    float* __restrict__ Pc) {
  __shared__ char smem[40960] __attribute__((aligned(128)));
  // flash: Ks [64][64]sh 0..8192; Vs [2] 8192..24576; Pb [2] 24576..40960.
  // gram path never touches smem.

  if (blockIdx.x >= 1200) {
    // ================= gram body (R4-proven, verbatim) =================
    int bid = blockIdx.x - 1200;
    int b = bid / 100, chunk = bid % 100;
    int n0 = chunk * 64;
    int t = threadIdx.x;
    int w = t >> 6, lane = t & 63;
    int quad = lane >> 4, l16 = lane & 15;
    size_t bc = (size_t)b * CH * NPIX;

    f32x4 acc[4];
#pragma unroll
    for (int ct = 0; ct < 4; ++ct) acc[ct] = (f32x4){0.f, 0.f, 0.f, 0.f};

    const unsigned int* kp = Kpk + bc + (size_t)(w * 16 + l16) * NPIX + n0;
    bf16x8 ah[2], al[2];
#pragma unroll
    for (int ks2 = 0; ks2 < 2; ++ks2) {
      uint4 ua = *(const uint4*)&kp[ks2 * 32 + quad * 8];
      uint4 ub = *(const uint4*)&kp[ks2 * 32 + quad * 8 + 4];
      deint(ua, ub, &ah[ks2], &al[ks2]);
    }
#pragma unroll
    for (int ct = 0; ct < 4; ++ct) {
      const unsigned int* qp = Qtn + bc + (size_t)(ct * 16 + l16) * NPIX + n0;
#pragma unroll
      for (int ks2 = 0; ks2 < 2; ++ks2) {
        uint4 va = *(const uint4*)&qp[ks2 * 32 + quad * 8];
        uint4 vb = *(const uint4*)&qp[ks2 * 32 + quad * 8 + 4];
        bf16x8 bh, bl;
        deint(va, vb, &bh, &bl);
        acc[ct] = __builtin_amdgcn_mfma_f32_16x16x32_bf16(ah[ks2], bh, acc[ct], 0, 0, 0);
        acc[ct] = __builtin_amdgcn_mfma_f32_16x16x32_bf16(ah[ks2], bl, acc[ct], 0, 0, 0);
        acc[ct] = __builtin_amdgcn_mfma_f32_16x16x32_bf16(al[ks2], bh, acc[ct], 0, 0, 0);
      }
    }
#pragma unroll
    for (int ct = 0; ct < 4; ++ct)
#pragma unroll
      for (int r = 0; r < 4; ++r)
        atomicAdd(&Pc[((size_t)b * 64 + w * 16 + quad * 4 + r) * 64 + ct * 16 + l16],
                  acc[ct][r]);
    return;
  }

  // ================= flash body (R11-proven, verbatim) =================
  int bid = blockIdx.x;
  int b = bid / 300;
  int rem = bid % 300;
  int qt = rem / 3, split = rem % 3;
  int p0 = qt * 64;
  int t = threadIdx.x;
  int w = t >> 6, lane = t & 63;
  int quad = lane >> 4, l16 = lane & 15;
  int sw = l16 & 7;
  size_t bq = (size_t)b * NPIX;
  size_t bC = (size_t)b * CH * NPIX;

  bf16x8 aq[2];
#pragma unroll
  for (int ks = 0; ks < 2; ++ks)
    aq[ks] = *(const bf16x8*)&Qtbf[(bq + p0 + w * 16 + l16) * 64 + ks * 32 + quad * 8];

  f32x4 oacc[4];
#pragma unroll
  for (int ct = 0; ct < 4; ++ct) oacc[ct] = (f32x4){0.f, 0.f, 0.f, 0.f};
  float psum = 0.f;

  const unsigned short* Kb = Qtbf + bq * 64;
  const unsigned short* Vb = Vbf + bC;
  int r0 = t >> 3, s0 = t & 7;  // r0 in [0,32)
  int r1 = r0 + 32;
  int wOff0 = r0 * 64 + ((s0 ^ (r0 & 7)) << 3);  // swizzled LDS dest (halves)
  int wOff1 = r1 * 64 + ((s0 ^ (r1 & 7)) << 3);

  int kt0 = split * 34;
  int niter = (split == 2) ? 32 : 34;

  unsigned short* Ks = (unsigned short*)smem;
  unsigned short* VsB = (unsigned short*)(smem + 8192);   // tile i at +(i&1)*4096 elems
  unsigned short* PbB = (unsigned short*)(smem + 24576);  // iter i at +(i&1)*4096 elems

  uint4 kreg0, kreg1, vreg0, vreg1;
  {  // load + stage tile 0 (A(0)); tile 0 parity = 0
    int n0 = kt0 * 64;
    kreg0 = *(const uint4*)&Kb[(size_t)(n0 + r0) * 64 + s0 * 8];
    vreg0 = *(const uint4*)&Vb[(size_t)r0 * NPIX + n0 + s0 * 8];
    kreg1 = *(const uint4*)&Kb[(size_t)(n0 + r1) * 64 + s0 * 8];
    vreg1 = *(const uint4*)&Vb[(size_t)r1 * NPIX + n0 + s0 * 8];
    *(uint4*)&Ks[wOff0] = kreg0;
    *(uint4*)&Ks[wOff1] = kreg1;
    *(uint4*)&VsB[wOff0] = vreg0;
    *(uint4*)&VsB[wOff1] = vreg1;
  }
  __syncthreads();  // tile 0 staged (this is bar2 of iter 0)

  for (int it = 0; it < niter; ++it) {
    if (it > 0) {
      __syncthreads();  // bar1: B(it-1) done reading Ks and Vs[it&1]
      // A(it): stage tile it from regs (loaded during B(it-1))
      unsigned short* Vn = VsB + ((it & 1) << 12);
      *(uint4*)&Ks[wOff0] = kreg0;
      *(uint4*)&Ks[wOff1] = kreg1;
      *(uint4*)&Vn[wOff0] = vreg0;
      *(uint4*)&Vn[wOff1] = vreg1;
      __syncthreads();  // bar2: tile it visible
    }
    // --- B(it) ---
    // early independent LDS reads of tile it-1 (P is wave-private; V via dbuf)
    bf16x8 pf[2], vf[8];
    if (it > 0) {
      unsigned short* Pprev = PbB + (((it - 1) & 1) << 12) + w * 1024;
      pf[0] = *(const bf16x8*)&Pprev[l16 * 64 + (((0 * 4 + quad) ^ sw) << 3)];
      pf[1] = *(const bf16x8*)&Pprev[l16 * 64 + (((1 * 4 + quad) ^ sw) << 3)];
      unsigned short* Vprev = VsB + (((it - 1) & 1) << 12);
#pragma unroll
      for (int ks = 0; ks < 2; ++ks)
#pragma unroll
        for (int ct = 0; ct < 4; ++ct)
          vf[ks * 4 + ct] = *(const bf16x8*)&Vprev[(ct * 16 + l16) * 64 +
                                                   (((ks * 4 + quad) ^ sw) << 3)];
    }
    // QK(it) on Ks, ESHIFT pre-subtracted via C-in
    f32x4 sc[4];
#pragma unroll
    for (int ct = 0; ct < 4; ++ct)
      sc[ct] = (f32x4){-ESHIFT, -ESHIFT, -ESHIFT, -ESHIFT};
    __builtin_amdgcn_s_setprio(1);
#pragma unroll
    for (int ks = 0; ks < 2; ++ks)
#pragma unroll
      for (int ct = 0; ct < 4; ++ct) {
        bf16x8 bk = *(const bf16x8*)&Ks[(ct * 16 + l16) * 64 +
                                        (((ks * 4 + quad) ^ sw) << 3)];
        sc[ct] = __builtin_amdgcn_mfma_f32_16x16x32_bf16(bk, aq[ks], sc[ct], 0, 0, 0);
      }
    __builtin_amdgcn_s_setprio(0);
    // issue global loads for tile it+1 (consumed at A(it+1))
    if (it + 1 < niter) {
      int n1 = (kt0 + it + 1) * 64;
      kreg0 = *(const uint4*)&Kb[(size_t)(n1 + r0) * 64 + s0 * 8];
      vreg0 = *(const uint4*)&Vb[(size_t)r0 * NPIX + n1 + s0 * 8];
      kreg1 = *(const uint4*)&Kb[(size_t)(n1 + r1) * 64 + s0 * 8];
      vreg1 = *(const uint4*)&Vb[(size_t)r1 * NPIX + n1 + s0 * 8];
    }
    // exp2 + pack -> Pb[it&1] (wave-private region)
    unsigned short* Pw = PbB + ((it & 1) << 12) + w * 1024;
#pragma unroll
    for (int ct = 0; ct < 4; ++ct) {
      float e0 = __builtin_amdgcn_exp2f(sc[ct][0]);
      float e1 = __builtin_amdgcn_exp2f(sc[ct][1]);
      float e2 = __builtin_amdgcn_exp2f(sc[ct][2]);
      float e3 = __builtin_amdgcn_exp2f(sc[ct][3]);
      psum += (e0 + e1) + (e2 + e3);
      unsigned int pk0, pk1;
      asm("v_cvt_pk_bf16_f32 %0, %1, %2" : "=v"(pk0) : "v"(e0), "v"(e1));
      asm("v_cvt_pk_bf16_f32 %0, %1, %2" : "=v"(pk1) : "v"(e2), "v"(e3));
      uint2 pk = {pk0, pk1};
      *(uint2*)&Pw[l16 * 64 +
                   (((2 * ct + (quad >> 1)) ^ sw) << 3) + ((quad & 1) << 2)] = pk;
    }
    // PV(it-1): inputs long since resident -> no stall
    if (it > 0) {
      __builtin_amdgcn_s_setprio(1);
#pragma unroll
      for (int ks = 0; ks < 2; ++ks)
#pragma unroll
        for (int ct = 0; ct < 4; ++ct)
          oacc[ct] = __builtin_amdgcn_mfma_f32_16x16x32_bf16(vf[ks * 4 + ct], pf[ks],
                                                             oacc[ct], 0, 0, 0);
      __builtin_amdgcn_s_setprio(0);
    }
  }
  // epilogue PV(niter-1)
  {
    bf16x8 pf[2], vf[8];
    unsigned short* Pprev = PbB + (((niter - 1) & 1) << 12) + w * 1024;
    pf[0] = *(const bf16x8*)&Pprev[l16 * 64 + (((0 * 4 + quad) ^ sw) << 3)];
    pf[1] = *(const bf16x8*)&Pprev[l16 * 64 + (((1 * 4 + quad) ^ sw) << 3)];
    unsigned short* Vprev = VsB + (((niter - 1) & 1) << 12);
#pragma unroll
    for (int ks = 0; ks < 2; ++ks)
#pragma unroll
      for (int ct = 0; ct < 4; ++ct)
        vf[ks * 4 + ct] = *(const bf16x8*)&Vprev[(ct * 16 + l16) * 64 +
                                                 (((ks * 4 + quad) ^ sw) << 3)];
#pragma unroll
    for (int ks = 0; ks < 2; ++ks)
#pragma unroll
      for (int ct = 0; ct < 4; ++ct)
        oacc[ct] = __builtin_amdgcn_mfma_f32_16x16x32_bf16(vf[ks * 4 + ct], pf[ks],
                                                           oacc[ct], 0, 0, 0);
  }
  // epilogue: direct stores (no atomics)
  float* Op = Opart + (size_t)(split * BATCH + b) * CH * NPIX;
  int pcol = p0 + w * 16 + l16;
  {
    float s = psum;
    s += __shfl_xor(s, 16, 64);
    s += __shfl_xor(s, 32, 64);
    if (quad == 0) Lpart[(size_t)(split * BATCH + b) * NPIX + pcol] = s;
  }
#pragma unroll
  for (int ct = 0; ct < 4; ++ct)
#pragma unroll
    for (int r = 0; r < 4; ++r)
      Op[(size_t)(ct * 16 + quad * 4 + r) * NPIX + pcol] = oacc[ct][r];
}

// ---------------- finalize ----------------
// v20-proven: channel-split 800 blocks (64 pixels x 32 output channels each).
__global__ __launch_bounds__(256) void finalize_kernel(
    const float* __restrict__ Pc, const unsigned short* __restrict__ Vbf,
    const float* __restrict__ Opart, const float* __restrict__ Lpart,
    float* __restrict__ out) {
  __shared__ float maT[64 * 32];  // [cp][c_local]
  int bid = blockIdx.x;
  int b = bid / 200;
  int rem = bid % 200;
  int nt = rem >> 1, half = rem & 1;
  int t = threadIdx.x;
  if (t < 32) {
    int c = half * 32 + t;
    const float* row = Pc + ((size_t)b * 64 + c) * 64;
    float v[64];
    float mx = -1e30f;
#pragma unroll
    for (int j = 0; j < 64; ++j) { v[j] = row[j]; mx = fmaxf(mx, v[j]); }
    float s = 0.f;
#pragma unroll
    for (int j = 0; j < 64; ++j) { v[j] = __expf(v[j] - mx); s += v[j]; }
    float inv = 1.f / s;
#pragma unroll
    for (int j = 0; j < 64; ++j) maT[j * 32 + t] = v[j] * inv;
  }
  __syncthreads();
  int lane = t & 63, ct = t >> 6;  // ct in [0,4): 8 channels each
  int n = nt * 64 + lane;
  size_t bc = (size_t)b * CH * NPIX;
  const unsigned short* vb = Vbf + bc + n;
  float acc[8];
#pragma unroll
  for (int j = 0; j < 8; ++j) acc[j] = 0.f;
  for (int cp = 0; cp < 64; ++cp) {
    float vv = bf2f(vb[(size_t)cp * NPIX]);
    const float* m = &maT[cp * 32 + ct * 8];
    f32x4 m0 = *(const f32x4*)&m[0];
    f32x4 m1 = *(const f32x4*)&m[4];
#pragma unroll
    for (int j = 0; j < 4; ++j) {
      acc[j] += m0[j] * vv;
      acc[4 + j] += m1[j] * vv;
    }
  }
  float lsum = Lpart[(size_t)(0 * BATCH + b) * NPIX + n] +
               Lpart[(size_t)(1 * BATCH + b) * NPIX + n] +
               Lpart[(size_t)(2 * BATCH + b) * NPIX + n];
  float inv = 1.f / lsum;
  const float* O0 = Opart + (size_t)(0 * BATCH + b) * CH * NPIX;
  const float* O1 = Opart + (size_t)(1 * BATCH + b) * CH * NPIX;
  const float* O2 = Opart + (size_t)(2 * BATCH + b) * CH * NPIX;
#pragma unroll
  for (int j = 0; j < 8; ++j) {
    size_t co = (size_t)(half * 32 + ct * 8 + j) * NPIX + n;
    float o = O0[co] + O1[co] + O2[co];
    out[bc + co] = acc[j] + o * inv;
  }
}

extern "C" void kernel_launch(void* const* d_in, const int* in_sizes, int n_in,
                              void* d_out, int out_size, void* d_ws, size_t ws_size,
                              hipStream_t stream) {
  const float* x = (const float*)d_in[0];
  const float* w = (const float*)d_in[1];
  const float* bias = (const float*)d_in[2];
  float* out = (float*)d_out;
  char* ws = (char*)d_ws;
  // layout (bytes):
  unsigned short* Qtbf = (unsigned short*)(ws);           // [0, 3276800)
  unsigned short* Vbf = (unsigned short*)(ws + 3276800);  // [3276800, 6553600)
  unsigned int* Kpk = (unsigned int*)(ws + 6553600);      // [6553600, 13107200) dead after fused
  unsigned int* Qtn = (unsigned int*)(ws + 13107200);     // [13107200, 19660800) dead after fused
  float* Opart = (float*)(ws + 19660800);                 // [19660800, 39321600) 3 splits
  float* Pc = (float*)(ws + 39321600);                    // [39321600, 39387136)
  float* Lpart = (float*)(ws + 39387136);                 // [39387136, 39694336)

  hipMemsetAsync(Pc, 0, 65536, stream);
  qkv_kernel<<<800, 512, 0, stream>>>(x, w, bias, Qtbf, Vbf, Kpk, Qtn);
  flashgram_kernel<<<1600, 256, 0, stream>>>(Qtbf, Vbf, Opart, Lpart, Kpk, Qtn, Pc);
  finalize_kernel<<<800, 256, 0, stream>>>(Pc, Vbf, Opart, Lpart, out);
}

// Round 22
// 167.714 us; speedup vs baseline: 1.0033x; 1.0033x over previous
//
#include <hip/hip_runtime.h>
#include <stdint.h>

#define BATCH 4
#define CH 64
#define HW 80
#define NPIX 6400
#define SPLITS 3

typedef __attribute__((ext_vector_type(8))) short bf16x8;
typedef __attribute__((ext_vector_type(4))) float f32x4;

#define QSCALE 1.2011224087864498f   // sqrt(log2(e))
#define ESHIFT 115.41560327111707f   // 80 * log2(e)

static __device__ __forceinline__ unsigned short f2bf(float f) {
  union { float f; unsigned int u; } v; v.f = f;
  unsigned int u = v.u;
  return (unsigned short)((u + 0x7fffu + ((u >> 16) & 1u)) >> 16);
}
static __device__ __forceinline__ float bf2f(unsigned short h) {
  union { unsigned int u; float f; } v; v.u = ((unsigned int)h) << 16;
  return v.f;
}
// fp32 -> (hi bf16 | lo bf16 << 16)
static __device__ __forceinline__ unsigned int split_pack(float a) {
  unsigned short hi = f2bf(a);
  union { unsigned int u; float f; } hf; hf.u = ((unsigned int)hi) << 16;
  unsigned short lo = f2bf(a - hf.f);
  return (unsigned int)hi | ((unsigned int)lo << 16);
}
// de-interleave 8 split-packed uints (2x uint4) into hi/lo bf16x8 fragments
static __device__ __forceinline__ void deint(uint4 a, uint4 b, bf16x8* h, bf16x8* l) {
  union { unsigned int u[4]; bf16x8 v; } H, L;
  H.u[0] = __builtin_amdgcn_perm(a.y, a.x, 0x05040100u);
  H.u[1] = __builtin_amdgcn_perm(a.w, a.z, 0x05040100u);
  H.u[2] = __builtin_amdgcn_perm(b.y, b.x, 0x05040100u);
  H.u[3] = __builtin_amdgcn_perm(b.w, b.z, 0x05040100u);
  L.u[0] = __builtin_amdgcn_perm(a.y, a.x, 0x07060302u);
  L.u[1] = __builtin_amdgcn_perm(a.w, a.z, 0x07060302u);
  L.u[2] = __builtin_amdgcn_perm(b.y, b.x, 0x07060302u);
  L.u[3] = __builtin_amdgcn_perm(b.w, b.z, 0x07060302u);
  *h = H.v; *l = L.v;
}

// ---------------- QKV 1x1 conv ----------------
// v16-proven: R4 scalar core + x-tile staged through LDS once (coalesced).
// (R21's output-split to 800 blocks regressed: staging overhead doubled while
// the FMA chain was already latency-hidden. Reverted.)
__global__ __launch_bounds__(512) void qkv_kernel(
    const float* __restrict__ x, const float* __restrict__ w,
    const float* __restrict__ bias, unsigned short* __restrict__ Qtbf,
    unsigned short* __restrict__ Vbf, unsigned int* __restrict__ Kpk,
    unsigned int* __restrict__ Qtn) {
  __shared__ float xs[64][65];  // [channel][pixel]
  __shared__ float qs[64][65];
  int bid = blockIdx.x;
  int b = bid / 100, tile = bid % 100;
  int p0 = tile * 64;
  int t = threadIdx.x;
  int i = t & 63;
  int og = __builtin_amdgcn_readfirstlane(t >> 6);  // 0..7
  int p = p0 + i;
  int tp = (p % HW) * HW + p / HW;  // involution transpose
  size_t bc = (size_t)b * CH * NPIX;
  // stage x[b][:, p0..p0+64) -> xs (coalesced: 8 threads/row x 8 floats)
  {
    int cr = t >> 3;         // channel 0..63
    int j0 = (t & 7) * 8;    // pixel chunk 0,8,..,56
    const float* xrow = x + bc + (size_t)cr * NPIX + p0 + j0;
    float4 xa = *(const float4*)&xrow[0];
    float4 xb4 = *(const float4*)&xrow[4];
    xs[cr][j0 + 0] = xa.x; xs[cr][j0 + 1] = xa.y;
    xs[cr][j0 + 2] = xa.z; xs[cr][j0 + 3] = xa.w;
    xs[cr][j0 + 4] = xb4.x; xs[cr][j0 + 5] = xb4.y;
    xs[cr][j0 + 6] = xb4.z; xs[cr][j0 + 7] = xb4.w;
  }
  __syncthreads();
  float xv[64];
#pragma unroll
  for (int c = 0; c < 64; ++c) xv[c] = xs[c][i];
  for (int j = 0; j < 24; j += 4) {
    int o = og * 24 + j;
    const float* wr0 = w + o * 64;
    const float* wr1 = wr0 + 64;
    const float* wr2 = wr0 + 128;
    const float* wr3 = wr0 + 192;
    float a0 = bias[o], a1 = bias[o + 1], a2 = bias[o + 2], a3 = bias[o + 3];
#pragma unroll
    for (int c = 0; c < 64; ++c) {
      float xc = xv[c];
      a0 += wr0[c] * xc;
      a1 += wr1[c] * xc;
      a2 += wr2[c] * xc;
      a3 += wr3[c] * xc;
    }
    float av[4] = {a0, a1, a2, a3};
#pragma unroll
    for (int u = 0; u < 4; ++u) {
      int oo = o + u;
      int cc = oo & 63;
      int kind = oo >> 6;
      float a = av[u];
      if (kind == 0) {
        qs[cc][i] = a;
        Qtn[bc + (size_t)cc * NPIX + tp] = split_pack(a);
      } else if (kind == 1) {
        Kpk[bc + (size_t)cc * NPIX + p] = split_pack(a);
      } else {
        Vbf[bc + (size_t)cc * NPIX + p] = f2bf(a);
      }
    }
  }
  __syncthreads();
  // restage q -> Qtbf rows (row 128B contiguous, scaled by QSCALE)
  int j2 = t >> 3, g = t & 7;  // j2 in [0,64), g in [0,8)
  int pj = p0 + j2;
  int tpj = (pj % HW) * HW + pj / HW;
  unsigned int pk4[4];
#pragma unroll
  for (int q4 = 0; q4 < 4; ++q4) {
    float a0 = qs[g * 8 + q4 * 2][j2] * QSCALE;
    float a1 = qs[g * 8 + q4 * 2 + 1][j2] * QSCALE;
    pk4[q4] = (unsigned int)f2bf(a0) | ((unsigned int)f2bf(a1) << 16);
  }
  unsigned short* dst = Qtbf + ((size_t)b * NPIX + tpj) * 64 + g * 8;
  uint4 w0 = {pk4[0], pk4[1], pk4[2], pk4[3]};
  *(uint4*)&dst[0] = w0;
}

// ---------------- fused flash + gram ----------------
// v19-proven: blocks 0-1199 = flash (R11 body), 1200-1599 = gram (R4 body).
// Gram blocks dispatch last -> fill flash's idle CU slots.
__global__ __launch_bounds__(256, 4) void flashgram_kernel(
    const unsigned short* __restrict__ Qtbf, const unsigned short* __restrict__ Vbf,
    float* __restrict__ Opart, float* __restrict__ Lpart,
    const unsigned int* __restrict__ Kpk, const unsigned int* __restrict__ Qtn,
    float* __restrict__ Pc) {
  __shared__ char smem[40960] __attribute__((aligned(128)));
  // flash: Ks [64][64]sh 0..8192; Vs [2] 8192..24576; Pb [2] 24576..40960.
  // gram path never touches smem.

  if (blockIdx.x >= 1200) {
    // ================= gram body (R4-proven, verbatim) =================
    int bid = blockIdx.x - 1200;
    int b = bid / 100, chunk = bid % 100;
    int n0 = chunk * 64;
    int t = threadIdx.x;
    int w = t >> 6, lane = t & 63;
    int quad = lane >> 4, l16 = lane & 15;
    size_t bc = (size_t)b * CH * NPIX;

    f32x4 acc[4];
#pragma unroll
    for (int ct = 0; ct < 4; ++ct) acc[ct] = (f32x4){0.f, 0.f, 0.f, 0.f};

    const unsigned int* kp = Kpk + bc + (size_t)(w * 16 + l16) * NPIX + n0;
    bf16x8 ah[2], al[2];
#pragma unroll
    for (int ks2 = 0; ks2 < 2; ++ks2) {
      uint4 ua = *(const uint4*)&kp[ks2 * 32 + quad * 8];
      uint4 ub = *(const uint4*)&kp[ks2 * 32 + quad * 8 + 4];
      deint(ua, ub, &ah[ks2], &al[ks2]);
    }
#pragma unroll
    for (int ct = 0; ct < 4; ++ct) {
      const unsigned int* qp = Qtn + bc + (size_t)(ct * 16 + l16) * NPIX + n0;
#pragma unroll
      for (int ks2 = 0; ks2 < 2; ++ks2) {
        uint4 va = *(const uint4*)&qp[ks2 * 32 + quad * 8];
        uint4 vb = *(const uint4*)&qp[ks2 * 32 + quad * 8 + 4];
        bf16x8 bh, bl;
        deint(va, vb, &bh, &bl);
        acc[ct] = __builtin_amdgcn_mfma_f32_16x16x32_bf16(ah[ks2], bh, acc[ct], 0, 0, 0);
        acc[ct] = __builtin_amdgcn_mfma_f32_16x16x32_bf16(ah[ks2], bl, acc[ct], 0, 0, 0);
        acc[ct] = __builtin_amdgcn_mfma_f32_16x16x32_bf16(al[ks2], bh, acc[ct], 0, 0, 0);
      }
    }
#pragma unroll
    for (int ct = 0; ct < 4; ++ct)
#pragma unroll
      for (int r = 0; r < 4; ++r)
        atomicAdd(&Pc[((size_t)b * 64 + w * 16 + quad * 4 + r) * 64 + ct * 16 + l16],
                  acc[ct][r]);
    return;
  }

  // ================= flash body (R11-proven, verbatim) =================
  int bid = blockIdx.x;
  int b = bid / 300;
  int rem = bid % 300;
  int qt = rem / 3, split = rem % 3;
  int p0 = qt * 64;
  int t = threadIdx.x;
  int w = t >> 6, lane = t & 63;
  int quad = lane >> 4, l16 = lane & 15;
  int sw = l16 & 7;
  size_t bq = (size_t)b * NPIX;
  size_t bC = (size_t)b * CH * NPIX;

  bf16x8 aq[2];
#pragma unroll
  for (int ks = 0; ks < 2; ++ks)
    aq[ks] = *(const bf16x8*)&Qtbf[(bq + p0 + w * 16 + l16) * 64 + ks * 32 + quad * 8];

  f32x4 oacc[4];
#pragma unroll
  for (int ct = 0; ct < 4; ++ct) oacc[ct] = (f32x4){0.f, 0.f, 0.f, 0.f};
  float psum = 0.f;

  const unsigned short* Kb = Qtbf + bq * 64;
  const unsigned short* Vb = Vbf + bC;
  int r0 = t >> 3, s0 = t & 7;  // r0 in [0,32)
  int r1 = r0 + 32;
  int wOff0 = r0 * 64 + ((s0 ^ (r0 & 7)) << 3);  // swizzled LDS dest (halves)
  int wOff1 = r1 * 64 + ((s0 ^ (r1 & 7)) << 3);

  int kt0 = split * 34;
  int niter = (split == 2) ? 32 : 34;

  unsigned short* Ks = (unsigned short*)smem;
  unsigned short* VsB = (unsigned short*)(smem + 8192);   // tile i at +(i&1)*4096 elems
  unsigned short* PbB = (unsigned short*)(smem + 24576);  // iter i at +(i&1)*4096 elems

  uint4 kreg0, kreg1, vreg0, vreg1;
  {  // load + stage tile 0 (A(0)); tile 0 parity = 0
    int n0 = kt0 * 64;
    kreg0 = *(const uint4*)&Kb[(size_t)(n0 + r0) * 64 + s0 * 8];
    vreg0 = *(const uint4*)&Vb[(size_t)r0 * NPIX + n0 + s0 * 8];
    kreg1 = *(const uint4*)&Kb[(size_t)(n0 + r1) * 64 + s0 * 8];
    vreg1 = *(const uint4*)&Vb[(size_t)r1 * NPIX + n0 + s0 * 8];
    *(uint4*)&Ks[wOff0] = kreg0;
    *(uint4*)&Ks[wOff1] = kreg1;
    *(uint4*)&VsB[wOff0] = vreg0;
    *(uint4*)&VsB[wOff1] = vreg1;
  }
  __syncthreads();  // tile 0 staged (this is bar2 of iter 0)

  for (int it = 0; it < niter; ++it) {
    if (it > 0) {
      __syncthreads();  // bar1: B(it-1) done reading Ks and Vs[it&1]
      // A(it): stage tile it from regs (loaded during B(it-1))
      unsigned short* Vn = VsB + ((it & 1) << 12);
      *(uint4*)&Ks[wOff0] = kreg0;
      *(uint4*)&Ks[wOff1] = kreg1;
      *(uint4*)&Vn[wOff0] = vreg0;
      *(uint4*)&Vn[wOff1] = vreg1;
      __syncthreads();  // bar2: tile it visible
    }
    // --- B(it) ---
    // early independent LDS reads of tile it-1 (P is wave-private; V via dbuf)
    bf16x8 pf[2], vf[8];
    if (it > 0) {
      unsigned short* Pprev = PbB + (((it - 1) & 1) << 12) + w * 1024;
      pf[0] = *(const bf16x8*)&Pprev[l16 * 64 + (((0 * 4 + quad) ^ sw) << 3)];
      pf[1] = *(const bf16x8*)&Pprev[l16 * 64 + (((1 * 4 + quad) ^ sw) << 3)];
      unsigned short* Vprev = VsB + (((it - 1) & 1) << 12);
#pragma unroll
      for (int ks = 0; ks < 2; ++ks)
#pragma unroll
        for (int ct = 0; ct < 4; ++ct)
          vf[ks * 4 + ct] = *(const bf16x8*)&Vprev[(ct * 16 + l16) * 64 +
                                                   (((ks * 4 + quad) ^ sw) << 3)];
    }
    // QK(it) on Ks, ESHIFT pre-subtracted via C-in
    f32x4 sc[4];
#pragma unroll
    for (int ct = 0; ct < 4; ++ct)
      sc[ct] = (f32x4){-ESHIFT, -ESHIFT, -ESHIFT, -ESHIFT};
    __builtin_amdgcn_s_setprio(1);
#pragma unroll
    for (int ks = 0; ks < 2; ++ks)
#pragma unroll
      for (int ct = 0; ct < 4; ++ct) {
        bf16x8 bk = *(const bf16x8*)&Ks[(ct * 16 + l16) * 64 +
                                        (((ks * 4 + quad) ^ sw) << 3)];
        sc[ct] = __builtin_amdgcn_mfma_f32_16x16x32_bf16(bk, aq[ks], sc[ct], 0, 0, 0);
      }
    __builtin_amdgcn_s_setprio(0);
    // issue global loads for tile it+1 (consumed at A(it+1))
    if (it + 1 < niter) {
      int n1 = (kt0 + it + 1) * 64;
      kreg0 = *(const uint4*)&Kb[(size_t)(n1 + r0) * 64 + s0 * 8];
      vreg0 = *(const uint4*)&Vb[(size_t)r0 * NPIX + n1 + s0 * 8];
      kreg1 = *(const uint4*)&Kb[(size_t)(n1 + r1) * 64 + s0 * 8];
      vreg1 = *(const uint4*)&Vb[(size_t)r1 * NPIX + n1 + s0 * 8];
    }
    // exp2 + pack -> Pb[it&1] (wave-private region)
    unsigned short* Pw = PbB + ((it & 1) << 12) + w * 1024;
#pragma unroll
    for (int ct = 0; ct < 4; ++ct) {
      float e0 = __builtin_amdgcn_exp2f(sc[ct][0]);
      float e1 = __builtin_amdgcn_exp2f(sc[ct][1]);
      float e2 = __builtin_amdgcn_exp2f(sc[ct][2]);
      float e3 = __builtin_amdgcn_exp2f(sc[ct][3]);
      psum += (e0 + e1) + (e2 + e3);
      unsigned int pk0, pk1;
      asm("v_cvt_pk_bf16_f32 %0, %1, %2" : "=v"(pk0) : "v"(e0), "v"(e1));
      asm("v_cvt_pk_bf16_f32 %0, %1, %2" : "=v"(pk1) : "v"(e2), "v"(e3));
      uint2 pk = {pk0, pk1};
      *(uint2*)&Pw[l16 * 64 +
                   (((2 * ct + (quad >> 1)) ^ sw) << 3) + ((quad & 1) << 2)] = pk;
    }
    // PV(it-1): inputs long since resident -> no stall
    if (it > 0) {
      __builtin_amdgcn_s_setprio(1);
#pragma unroll
      for (int ks = 0; ks < 2; ++ks)
#pragma unroll
        for (int ct = 0; ct < 4; ++ct)
          oacc[ct] = __builtin_amdgcn_mfma_f32_16x16x32_bf16(vf[ks * 4 + ct], pf[ks],
                                                             oacc[ct], 0, 0, 0);
      __builtin_amdgcn_s_setprio(0);
    }
  }
  // epilogue PV(niter-1)
  {
    bf16x8 pf[2], vf[8];
    unsigned short* Pprev = PbB + (((niter - 1) & 1) << 12) + w * 1024;
    pf[0] = *(const bf16x8*)&Pprev[l16 * 64 + (((0 * 4 + quad) ^ sw) << 3)];
    pf[1] = *(const bf16x8*)&Pprev[l16 * 64 + (((1 * 4 + quad) ^ sw) << 3)];
    unsigned short* Vprev = VsB + (((niter - 1) & 1) << 12);
#pragma unroll
    for (int ks = 0; ks < 2; ++ks)
#pragma unroll
      for (int ct = 0; ct < 4; ++ct)
        vf[ks * 4 + ct] = *(const bf16x8*)&Vprev[(ct * 16 + l16) * 64 +
                                                 (((ks * 4 + quad) ^ sw) << 3)];
#pragma unroll
    for (int ks = 0; ks < 2; ++ks)
#pragma unroll
      for (int ct = 0; ct < 4; ++ct)
        oacc[ct] = __builtin_amdgcn_mfma_f32_16x16x32_bf16(vf[ks * 4 + ct], pf[ks],
                                                           oacc[ct], 0, 0, 0);
  }
  // epilogue: direct stores (no atomics)
  float* Op = Opart + (size_t)(split * BATCH + b) * CH * NPIX;
  int pcol = p0 + w * 16 + l16;
  {
    float s = psum;
    s += __shfl_xor(s, 16, 64);
    s += __shfl_xor(s, 32, 64);
    if (quad == 0) Lpart[(size_t)(split * BATCH + b) * NPIX + pcol] = s;
  }
#pragma unroll
  for (int ct = 0; ct < 4; ++ct)
#pragma unroll
    for (int r = 0; r < 4; ++r)
      Op[(size_t)(ct * 16 + quad * 4 + r) * NPIX + pcol] = oacc[ct][r];
}

// ---------------- finalize ----------------
// v20-proven: channel-split 800 blocks (64 pixels x 32 output channels each).
__global__ __launch_bounds__(256) void finalize_kernel(
    const float* __restrict__ Pc, const unsigned short* __restrict__ Vbf,
    const float* __restrict__ Opart, const float* __restrict__ Lpart,
    float* __restrict__ out) {
  __shared__ float maT[64 * 32];  // [cp][c_local]
  int bid = blockIdx.x;
  int b = bid / 200;
  int rem = bid % 200;
  int nt = rem >> 1, half = rem & 1;
  int t = threadIdx.x;
  if (t < 32) {
    int c = half * 32 + t;
    const float* row = Pc + ((size_t)b * 64 + c) * 64;
    float v[64];
    float mx = -1e30f;
#pragma unroll
    for (int j = 0; j < 64; ++j) { v[j] = row[j]; mx = fmaxf(mx, v[j]); }
    float s = 0.f;
#pragma unroll
    for (int j = 0; j < 64; ++j) { v[j] = __expf(v[j] - mx); s += v[j]; }
    float inv = 1.f / s;
#pragma unroll
    for (int j = 0; j < 64; ++j) maT[j * 32 + t] = v[j] * inv;
  }
  __syncthreads();
  int lane = t & 63, ct = t >> 6;  // ct in [0,4): 8 channels each
  int n = nt * 64 + lane;
  size_t bc = (size_t)b * CH * NPIX;
  const unsigned short* vb = Vbf + bc + n;
  float acc[8];
#pragma unroll
  for (int j = 0; j < 8; ++j) acc[j] = 0.f;
  for (int cp = 0; cp < 64; ++cp) {
    float vv = bf2f(vb[(size_t)cp * NPIX]);
    const float* m = &maT[cp * 32 + ct * 8];
    f32x4 m0 = *(const f32x4*)&m[0];
    f32x4 m1 = *(const f32x4*)&m[4];
#pragma unroll
    for (int j = 0; j < 4; ++j) {
      acc[j] += m0[j] * vv;
      acc[4 + j] += m1[j] * vv;
    }
  }
  float lsum = Lpart[(size_t)(0 * BATCH + b) * NPIX + n] +
               Lpart[(size_t)(1 * BATCH + b) * NPIX + n] +
               Lpart[(size_t)(2 * BATCH + b) * NPIX + n];
  float inv = 1.f / lsum;
  const float* O0 = Opart + (size_t)(0 * BATCH + b) * CH * NPIX;
  const float* O1 = Opart + (size_t)(1 * BATCH + b) * CH * NPIX;
  const float* O2 = Opart + (size_t)(2 * BATCH + b) * CH * NPIX;
#pragma unroll
  for (int j = 0; j < 8; ++j) {
    size_t co = (size_t)(half * 32 + ct * 8 + j) * NPIX + n;
    float o = O0[co] + O1[co] + O2[co];
    out[bc + co] = acc[j] + o * inv;
  }
}

extern "C" void kernel_launch(void* const* d_in, const int* in_sizes, int n_in,
                              void* d_out, int out_size, void* d_ws, size_t ws_size,
                              hipStream_t stream) {
  const float* x = (const float*)d_in[0];
  const float* w = (const float*)d_in[1];
  const float* bias = (const float*)d_in[2];
  float* out = (float*)d_out;
  char* ws = (char*)d_ws;
  // layout (bytes):
  unsigned short* Qtbf = (unsigned short*)(ws);           // [0, 3276800)
  unsigned short* Vbf = (unsigned short*)(ws + 3276800);  // [3276800, 6553600)
  unsigned int* Kpk = (unsigned int*)(ws + 6553600);      // [6553600, 13107200) dead after fused
  unsigned int* Qtn = (unsigned int*)(ws + 13107200);     // [13107200, 19660800) dead after fused
  float* Opart = (float*)(ws + 19660800);                 // [19660800, 39321600) 3 splits
  float* Pc = (float*)(ws + 39321600);                    // [39321600, 39387136)
  float* Lpart = (float*)(ws + 39387136);                 // [39387136, 39694336)

  hipMemsetAsync(Pc, 0, 65536, stream);
  qkv_kernel<<<400, 512, 0, stream>>>(x, w, bias, Qtbf, Vbf, Kpk, Qtn);
  flashgram_kernel<<<1600, 256, 0, stream>>>(Qtbf, Vbf, Opart, Lpart, Kpk, Qtn, Pc);
  finalize_kernel<<<800, 256, 0, stream>>>(Pc, Vbf, Opart, Lpart, out);
}

// Round 23
// 162.809 us; speedup vs baseline: 1.0335x; 1.0301x over previous
//
#include <hip/hip_runtime.h>
#include <stdint.h>

#define BATCH 4
#define CH 64
#define HW 80
#define NPIX 6400
#define SPLITS 3

typedef __attribute__((ext_vector_type(8))) short bf16x8;
typedef __attribute__((ext_vector_type(4))) float f32x4;

#define QSCALE 1.2011224087864498f   // sqrt(log2(e))
#define ESHIFT 115.41560327111707f   // 80 * log2(e)

static __device__ __forceinline__ unsigned short f2bf(float f) {
  union { float f; unsigned int u; } v; v.f = f;
  unsigned int u = v.u;
  return (unsigned short)((u + 0x7fffu + ((u >> 16) & 1u)) >> 16);
}
static __device__ __forceinline__ float bf2f(unsigned short h) {
  union { unsigned int u; float f; } v; v.u = ((unsigned int)h) << 16;
  return v.f;
}
// fp32 -> (hi bf16 | lo bf16 << 16)
static __device__ __forceinline__ unsigned int split_pack(float a) {
  unsigned short hi = f2bf(a);
  union { unsigned int u; float f; } hf; hf.u = ((unsigned int)hi) << 16;
  unsigned short lo = f2bf(a - hf.f);
  return (unsigned int)hi | ((unsigned int)lo << 16);
}
// de-interleave 8 split-packed uints (2x uint4) into hi/lo bf16x8 fragments
static __device__ __forceinline__ void deint(uint4 a, uint4 b, bf16x8* h, bf16x8* l) {
  union { unsigned int u[4]; bf16x8 v; } H, L;
  H.u[0] = __builtin_amdgcn_perm(a.y, a.x, 0x05040100u);
  H.u[1] = __builtin_amdgcn_perm(a.w, a.z, 0x05040100u);
  H.u[2] = __builtin_amdgcn_perm(b.y, b.x, 0x05040100u);
  H.u[3] = __builtin_amdgcn_perm(b.w, b.z, 0x05040100u);
  L.u[0] = __builtin_amdgcn_perm(a.y, a.x, 0x07060302u);
  L.u[1] = __builtin_amdgcn_perm(a.w, a.z, 0x07060302u);
  L.u[2] = __builtin_amdgcn_perm(b.y, b.x, 0x07060302u);
  L.u[3] = __builtin_amdgcn_perm(b.w, b.z, 0x07060302u);
  *h = H.v; *l = L.v;
}

// ---------------- QKV 1x1 conv ----------------
// v16-proven: R4 scalar core + x-tile staged through LDS once (coalesced).
__global__ __launch_bounds__(512) void qkv_kernel(
    const float* __restrict__ x, const float* __restrict__ w,
    const float* __restrict__ bias, unsigned short* __restrict__ Qtbf,
    unsigned short* __restrict__ Vbf, unsigned int* __restrict__ Kpk,
    unsigned int* __restrict__ Qtn) {
  __shared__ float xs[64][65];  // [channel][pixel]
  __shared__ float qs[64][65];
  int bid = blockIdx.x;
  int b = bid / 100, tile = bid % 100;
  int p0 = tile * 64;
  int t = threadIdx.x;
  int i = t & 63;
  int og = __builtin_amdgcn_readfirstlane(t >> 6);  // 0..7
  int p = p0 + i;
  int tp = (p % HW) * HW + p / HW;  // involution transpose
  size_t bc = (size_t)b * CH * NPIX;
  // stage x[b][:, p0..p0+64) -> xs (coalesced: 8 threads/row x 8 floats)
  {
    int cr = t >> 3;         // channel 0..63
    int j0 = (t & 7) * 8;    // pixel chunk 0,8,..,56
    const float* xrow = x + bc + (size_t)cr * NPIX + p0 + j0;
    float4 xa = *(const float4*)&xrow[0];
    float4 xb4 = *(const float4*)&xrow[4];
    xs[cr][j0 + 0] = xa.x; xs[cr][j0 + 1] = xa.y;
    xs[cr][j0 + 2] = xa.z; xs[cr][j0 + 3] = xa.w;
    xs[cr][j0 + 4] = xb4.x; xs[cr][j0 + 5] = xb4.y;
    xs[cr][j0 + 6] = xb4.z; xs[cr][j0 + 7] = xb4.w;
  }
  __syncthreads();
  float xv[64];
#pragma unroll
  for (int c = 0; c < 64; ++c) xv[c] = xs[c][i];
  for (int j = 0; j < 24; j += 4) {
    int o = og * 24 + j;
    const float* wr0 = w + o * 64;
    const float* wr1 = wr0 + 64;
    const float* wr2 = wr0 + 128;
    const float* wr3 = wr0 + 192;
    float a0 = bias[o], a1 = bias[o + 1], a2 = bias[o + 2], a3 = bias[o + 3];
#pragma unroll
    for (int c = 0; c < 64; ++c) {
      float xc = xv[c];
      a0 += wr0[c] * xc;
      a1 += wr1[c] * xc;
      a2 += wr2[c] * xc;
      a3 += wr3[c] * xc;
    }
    float av[4] = {a0, a1, a2, a3};
#pragma unroll
    for (int u = 0; u < 4; ++u) {
      int oo = o + u;
      int cc = oo & 63;
      int kind = oo >> 6;
      float a = av[u];
      if (kind == 0) {
        qs[cc][i] = a;
        Qtn[bc + (size_t)cc * NPIX + tp] = split_pack(a);
      } else if (kind == 1) {
        Kpk[bc + (size_t)cc * NPIX + p] = split_pack(a);
      } else {
        Vbf[bc + (size_t)cc * NPIX + p] = f2bf(a);
      }
    }
  }
  __syncthreads();
  // restage q -> Qtbf rows (row 128B contiguous, scaled by QSCALE)
  int j2 = t >> 3, g = t & 7;  // j2 in [0,64), g in [0,8)
  int pj = p0 + j2;
  int tpj = (pj % HW) * HW + pj / HW;
  unsigned int pk4[4];
#pragma unroll
  for (int q4 = 0; q4 < 4; ++q4) {
    float a0 = qs[g * 8 + q4 * 2][j2] * QSCALE;
    float a1 = qs[g * 8 + q4 * 2 + 1][j2] * QSCALE;
    pk4[q4] = (unsigned int)f2bf(a0) | ((unsigned int)f2bf(a1) << 16);
  }
  unsigned short* dst = Qtbf + ((size_t)b * NPIX + tpj) * 64 + g * 8;
  uint4 w0 = {pk4[0], pk4[1], pk4[2], pk4[3]};
  *(uint4*)&dst[0] = w0;
}

// ---------------- fused flash + gram ----------------
// v23: v19 fused structure; flash epilogue now accumulates into a SINGLE
// zero-initialized O/L buffer via atomicAdd (each address hit exactly 3x,
// once per split) instead of writing 3x fp32 partials. Cuts finalize's
// Opart read set 19.6MB -> 6.5MB and Lpart 3 -> 1 rows.
__global__ __launch_bounds__(256, 4) void flashgram_kernel(
    const unsigned short* __restrict__ Qtbf, const unsigned short* __restrict__ Vbf,
    float* __restrict__ Oacc, float* __restrict__ Lacc,
    const unsigned int* __restrict__ Kpk, const unsigned int* __restrict__ Qtn,
    float* __restrict__ Pc) {
  __shared__ char smem[40960] __attribute__((aligned(128)));
  // flash: Ks [64][64]sh 0..8192; Vs [2] 8192..24576; Pb [2] 24576..40960.
  // gram path never touches smem.

  if (blockIdx.x >= 1200) {
    // ================= gram body (R4-proven, verbatim) =================
    int bid = blockIdx.x - 1200;
    int b = bid / 100, chunk = bid % 100;
    int n0 = chunk * 64;
    int t = threadIdx.x;
    int w = t >> 6, lane = t & 63;
    int quad = lane >> 4, l16 = lane & 15;
    size_t bc = (size_t)b * CH * NPIX;

    f32x4 acc[4];
#pragma unroll
    for (int ct = 0; ct < 4; ++ct) acc[ct] = (f32x4){0.f, 0.f, 0.f, 0.f};

    const unsigned int* kp = Kpk + bc + (size_t)(w * 16 + l16) * NPIX + n0;
    bf16x8 ah[2], al[2];
#pragma unroll
    for (int ks2 = 0; ks2 < 2; ++ks2) {
      uint4 ua = *(const uint4*)&kp[ks2 * 32 + quad * 8];
      uint4 ub = *(const uint4*)&kp[ks2 * 32 + quad * 8 + 4];
      deint(ua, ub, &ah[ks2], &al[ks2]);
    }
#pragma unroll
    for (int ct = 0; ct < 4; ++ct) {
      const unsigned int* qp = Qtn + bc + (size_t)(ct * 16 + l16) * NPIX + n0;
#pragma unroll
      for (int ks2 = 0; ks2 < 2; ++ks2) {
        uint4 va = *(const uint4*)&qp[ks2 * 32 + quad * 8];
        uint4 vb = *(const uint4*)&qp[ks2 * 32 + quad * 8 + 4];
        bf16x8 bh, bl;
        deint(va, vb, &bh, &bl);
        acc[ct] = __builtin_amdgcn_mfma_f32_16x16x32_bf16(ah[ks2], bh, acc[ct], 0, 0, 0);
        acc[ct] = __builtin_amdgcn_mfma_f32_16x16x32_bf16(ah[ks2], bl, acc[ct], 0, 0, 0);
        acc[ct] = __builtin_amdgcn_mfma_f32_16x16x32_bf16(al[ks2], bh, acc[ct], 0, 0, 0);
      }
    }
#pragma unroll
    for (int ct = 0; ct < 4; ++ct)
#pragma unroll
      for (int r = 0; r < 4; ++r)
        atomicAdd(&Pc[((size_t)b * 64 + w * 16 + quad * 4 + r) * 64 + ct * 16 + l16],
                  acc[ct][r]);
    return;
  }

  // ================= flash body (R11-proven core) =================
  int bid = blockIdx.x;
  int b = bid / 300;
  int rem = bid % 300;
  int qt = rem / 3, split = rem % 3;
  int p0 = qt * 64;
  int t = threadIdx.x;
  int w = t >> 6, lane = t & 63;
  int quad = lane >> 4, l16 = lane & 15;
  int sw = l16 & 7;
  size_t bq = (size_t)b * NPIX;
  size_t bC = (size_t)b * CH * NPIX;

  bf16x8 aq[2];
#pragma unroll
  for (int ks = 0; ks < 2; ++ks)
    aq[ks] = *(const bf16x8*)&Qtbf[(bq + p0 + w * 16 + l16) * 64 + ks * 32 + quad * 8];

  f32x4 oacc[4];
#pragma unroll
  for (int ct = 0; ct < 4; ++ct) oacc[ct] = (f32x4){0.f, 0.f, 0.f, 0.f};
  float psum = 0.f;

  const unsigned short* Kb = Qtbf + bq * 64;
  const unsigned short* Vb = Vbf + bC;
  int r0 = t >> 3, s0 = t & 7;  // r0 in [0,32)
  int r1 = r0 + 32;
  int wOff0 = r0 * 64 + ((s0 ^ (r0 & 7)) << 3);  // swizzled LDS dest (halves)
  int wOff1 = r1 * 64 + ((s0 ^ (r1 & 7)) << 3);

  int kt0 = split * 34;
  int niter = (split == 2) ? 32 : 34;

  unsigned short* Ks = (unsigned short*)smem;
  unsigned short* VsB = (unsigned short*)(smem + 8192);   // tile i at +(i&1)*4096 elems
  unsigned short* PbB = (unsigned short*)(smem + 24576);  // iter i at +(i&1)*4096 elems

  uint4 kreg0, kreg1, vreg0, vreg1;
  {  // load + stage tile 0 (A(0)); tile 0 parity = 0
    int n0 = kt0 * 64;
    kreg0 = *(const uint4*)&Kb[(size_t)(n0 + r0) * 64 + s0 * 8];
    vreg0 = *(const uint4*)&Vb[(size_t)r0 * NPIX + n0 + s0 * 8];
    kreg1 = *(const uint4*)&Kb[(size_t)(n0 + r1) * 64 + s0 * 8];
    vreg1 = *(const uint4*)&Vb[(size_t)r1 * NPIX + n0 + s0 * 8];
    *(uint4*)&Ks[wOff0] = kreg0;
    *(uint4*)&Ks[wOff1] = kreg1;
    *(uint4*)&VsB[wOff0] = vreg0;
    *(uint4*)&VsB[wOff1] = vreg1;
  }
  __syncthreads();  // tile 0 staged (this is bar2 of iter 0)

  for (int it = 0; it < niter; ++it) {
    if (it > 0) {
      __syncthreads();  // bar1: B(it-1) done reading Ks and Vs[it&1]
      // A(it): stage tile it from regs (loaded during B(it-1))
      unsigned short* Vn = VsB + ((it & 1) << 12);
      *(uint4*)&Ks[wOff0] = kreg0;
      *(uint4*)&Ks[wOff1] = kreg1;
      *(uint4*)&Vn[wOff0] = vreg0;
      *(uint4*)&Vn[wOff1] = vreg1;
      __syncthreads();  // bar2: tile it visible
    }
    // --- B(it) ---
    // early independent LDS reads of tile it-1 (P is wave-private; V via dbuf)
    bf16x8 pf[2], vf[8];
    if (it > 0) {
      unsigned short* Pprev = PbB + (((it - 1) & 1) << 12) + w * 1024;
      pf[0] = *(const bf16x8*)&Pprev[l16 * 64 + (((0 * 4 + quad) ^ sw) << 3)];
      pf[1] = *(const bf16x8*)&Pprev[l16 * 64 + (((1 * 4 + quad) ^ sw) << 3)];
      unsigned short* Vprev = VsB + (((it - 1) & 1) << 12);
#pragma unroll
      for (int ks = 0; ks < 2; ++ks)
#pragma unroll
        for (int ct = 0; ct < 4; ++ct)
          vf[ks * 4 + ct] = *(const bf16x8*)&Vprev[(ct * 16 + l16) * 64 +
                                                   (((ks * 4 + quad) ^ sw) << 3)];
    }
    // QK(it) on Ks, ESHIFT pre-subtracted via C-in
    f32x4 sc[4];
#pragma unroll
    for (int ct = 0; ct < 4; ++ct)
      sc[ct] = (f32x4){-ESHIFT, -ESHIFT, -ESHIFT, -ESHIFT};
    __builtin_amdgcn_s_setprio(1);
#pragma unroll
    for (int ks = 0; ks < 2; ++ks)
#pragma unroll
      for (int ct = 0; ct < 4; ++ct) {
        bf16x8 bk = *(const bf16x8*)&Ks[(ct * 16 + l16) * 64 +
                                        (((ks * 4 + quad) ^ sw) << 3)];
        sc[ct] = __builtin_amdgcn_mfma_f32_16x16x32_bf16(bk, aq[ks], sc[ct], 0, 0, 0);
      }
    __builtin_amdgcn_s_setprio(0);
    // issue global loads for tile it+1 (consumed at A(it+1))
    if (it + 1 < niter) {
      int n1 = (kt0 + it + 1) * 64;
      kreg0 = *(const uint4*)&Kb[(size_t)(n1 + r0) * 64 + s0 * 8];
      vreg0 = *(const uint4*)&Vb[(size_t)r0 * NPIX + n1 + s0 * 8];
      kreg1 = *(const uint4*)&Kb[(size_t)(n1 + r1) * 64 + s0 * 8];
      vreg1 = *(const uint4*)&Vb[(size_t)r1 * NPIX + n1 + s0 * 8];
    }
    // exp2 + pack -> Pb[it&1] (wave-private region)
    unsigned short* Pw = PbB + ((it & 1) << 12) + w * 1024;
#pragma unroll
    for (int ct = 0; ct < 4; ++ct) {
      float e0 = __builtin_amdgcn_exp2f(sc[ct][0]);
      float e1 = __builtin_amdgcn_exp2f(sc[ct][1]);
      float e2 = __builtin_amdgcn_exp2f(sc[ct][2]);
      float e3 = __builtin_amdgcn_exp2f(sc[ct][3]);
      psum += (e0 + e1) + (e2 + e3);
      unsigned int pk0, pk1;
      asm("v_cvt_pk_bf16_f32 %0, %1, %2" : "=v"(pk0) : "v"(e0), "v"(e1));
      asm("v_cvt_pk_bf16_f32 %0, %1, %2" : "=v"(pk1) : "v"(e2), "v"(e3));
      uint2 pk = {pk0, pk1};
      *(uint2*)&Pw[l16 * 64 +
                   (((2 * ct + (quad >> 1)) ^ sw) << 3) + ((quad & 1) << 2)] = pk;
    }
    // PV(it-1): inputs long since resident -> no stall
    if (it > 0) {
      __builtin_amdgcn_s_setprio(1);
#pragma unroll
      for (int ks = 0; ks < 2; ++ks)
#pragma unroll
        for (int ct = 0; ct < 4; ++ct)
          oacc[ct] = __builtin_amdgcn_mfma_f32_16x16x32_bf16(vf[ks * 4 + ct], pf[ks],
                                                             oacc[ct], 0, 0, 0);
      __builtin_amdgcn_s_setprio(0);
    }
  }
  // epilogue PV(niter-1)
  {
    bf16x8 pf[2], vf[8];
    unsigned short* Pprev = PbB + (((niter - 1) & 1) << 12) + w * 1024;
    pf[0] = *(const bf16x8*)&Pprev[l16 * 64 + (((0 * 4 + quad) ^ sw) << 3)];
    pf[1] = *(const bf16x8*)&Pprev[l16 * 64 + (((1 * 4 + quad) ^ sw) << 3)];
    unsigned short* Vprev = VsB + (((niter - 1) & 1) << 12);
#pragma unroll
    for (int ks = 0; ks < 2; ++ks)
#pragma unroll
      for (int ct = 0; ct < 4; ++ct)
        vf[ks * 4 + ct] = *(const bf16x8*)&Vprev[(ct * 16 + l16) * 64 +
                                                 (((ks * 4 + quad) ^ sw) << 3)];
#pragma unroll
    for (int ks = 0; ks < 2; ++ks)
#pragma unroll
      for (int ct = 0; ct < 4; ++ct)
        oacc[ct] = __builtin_amdgcn_mfma_f32_16x16x32_bf16(vf[ks * 4 + ct], pf[ks],
                                                           oacc[ct], 0, 0, 0);
  }
  // epilogue: atomic split-K reduction into single O/L (zero-init'd per launch)
  float* Op = Oacc + bC;
  int pcol = p0 + w * 16 + l16;
  {
    float s = psum;
    s += __shfl_xor(s, 16, 64);
    s += __shfl_xor(s, 32, 64);
    if (quad == 0) atomicAdd(&Lacc[bq + pcol], s);
  }
#pragma unroll
  for (int ct = 0; ct < 4; ++ct)
#pragma unroll
    for (int r = 0; r < 4; ++r)
      atomicAdd(&Op[(size_t)(ct * 16 + quad * 4 + r) * NPIX + pcol], oacc[ct][r]);
}

// ---------------- finalize ----------------
// v23: reads single pre-reduced O (6.5MB, was 19.6MB of partials) and single
// L row. v20's 800-block channel-split retained.
__global__ __launch_bounds__(256) void finalize_kernel(
    const float* __restrict__ Pc, const unsigned short* __restrict__ Vbf,
    const float* __restrict__ Oacc, const float* __restrict__ Lacc,
    float* __restrict__ out) {
  __shared__ float maT[64 * 32];  // [cp][c_local]
  int bid = blockIdx.x;
  int b = bid / 200;
  int rem = bid % 200;
  int nt = rem >> 1, half = rem & 1;
  int t = threadIdx.x;
  if (t < 32) {
    int c = half * 32 + t;
    const float* row = Pc + ((size_t)b * 64 + c) * 64;
    float v[64];
    float mx = -1e30f;
#pragma unroll
    for (int j = 0; j < 64; ++j) { v[j] = row[j]; mx = fmaxf(mx, v[j]); }
    float s = 0.f;
#pragma unroll
    for (int j = 0; j < 64; ++j) { v[j] = __expf(v[j] - mx); s += v[j]; }
    float inv = 1.f / s;
#pragma unroll
    for (int j = 0; j < 64; ++j) maT[j * 32 + t] = v[j] * inv;
  }
  __syncthreads();
  int lane = t & 63, ct = t >> 6;  // ct in [0,4): 8 channels each
  int n = nt * 64 + lane;
  size_t bc = (size_t)b * CH * NPIX;
  const unsigned short* vb = Vbf + bc + n;
  float acc[8];
#pragma unroll
  for (int j = 0; j < 8; ++j) acc[j] = 0.f;
  for (int cp = 0; cp < 64; ++cp) {
    float vv = bf2f(vb[(size_t)cp * NPIX]);
    const float* m = &maT[cp * 32 + ct * 8];
    f32x4 m0 = *(const f32x4*)&m[0];
    f32x4 m1 = *(const f32x4*)&m[4];
#pragma unroll
    for (int j = 0; j < 4; ++j) {
      acc[j] += m0[j] * vv;
      acc[4 + j] += m1[j] * vv;
    }
  }
  float inv = 1.f / Lacc[(size_t)b * NPIX + n];
  const float* O0 = Oacc + bc;
#pragma unroll
  for (int j = 0; j < 8; ++j) {
    size_t co = (size_t)(half * 32 + ct * 8 + j) * NPIX + n;
    out[bc + co] = acc[j] + O0[co] * inv;
  }
}

extern "C" void kernel_launch(void* const* d_in, const int* in_sizes, int n_in,
                              void* d_out, int out_size, void* d_ws, size_t ws_size,
                              hipStream_t stream) {
  const float* x = (const float*)d_in[0];
  const float* w = (const float*)d_in[1];
  const float* bias = (const float*)d_in[2];
  float* out = (float*)d_out;
  char* ws = (char*)d_ws;
  // layout (bytes):
  unsigned short* Qtbf = (unsigned short*)(ws);           // [0, 3276800)
  unsigned short* Vbf = (unsigned short*)(ws + 3276800);  // [3276800, 6553600)
  unsigned int* Kpk = (unsigned int*)(ws + 6553600);      // [6553600, 13107200)
  unsigned int* Qtn = (unsigned int*)(ws + 13107200);     // [13107200, 19660800)
  float* Oacc = (float*)(ws + 19660800);                  // [19660800, 26214400) single fp32 O
  float* Pc = (float*)(ws + 26214400);                    // [26214400, 26279936)
  float* Lacc = (float*)(ws + 26279936);                  // [26279936, 26382336) single L
  // zero O + Pc + L in one contiguous memset (6721536 B), inside the graph
  hipMemsetAsync(ws + 19660800, 0, 6721536, stream);
  qkv_kernel<<<400, 512, 0, stream>>>(x, w, bias, Qtbf, Vbf, Kpk, Qtn);
  flashgram_kernel<<<1600, 256, 0, stream>>>(Qtbf, Vbf, Oacc, Lacc, Kpk, Qtn, Pc);
  finalize_kernel<<<800, 256, 0, stream>>>(Pc, Vbf, Oacc, Lacc, out);
}

// Round 24
// 160.236 us; speedup vs baseline: 1.0501x; 1.0161x over previous
//
#include <hip/hip_runtime.h>
#include <stdint.h>

#define BATCH 4
#define CH 64
#define HW 80
#define NPIX 6400
#define SPLITS 3

typedef __attribute__((ext_vector_type(8))) short bf16x8;
typedef __attribute__((ext_vector_type(4))) float f32x4;

#define QSCALE 1.2011224087864498f   // sqrt(log2(e))
#define ESHIFT 115.41560327111707f   // 80 * log2(e)

static __device__ __forceinline__ unsigned short f2bf(float f) {
  union { float f; unsigned int u; } v; v.f = f;
  unsigned int u = v.u;
  return (unsigned short)((u + 0x7fffu + ((u >> 16) & 1u)) >> 16);
}
static __device__ __forceinline__ float bf2f(unsigned short h) {
  union { unsigned int u; float f; } v; v.u = ((unsigned int)h) << 16;
  return v.f;
}
// fp32 -> (hi bf16 | lo bf16 << 16)
static __device__ __forceinline__ unsigned int split_pack(float a) {
  unsigned short hi = f2bf(a);
  union { unsigned int u; float f; } hf; hf.u = ((unsigned int)hi) << 16;
  unsigned short lo = f2bf(a - hf.f);
  return (unsigned int)hi | ((unsigned int)lo << 16);
}
// de-interleave 8 split-packed uints (2x uint4) into hi/lo bf16x8 fragments
static __device__ __forceinline__ void deint(uint4 a, uint4 b, bf16x8* h, bf16x8* l) {
  union { unsigned int u[4]; bf16x8 v; } H, L;
  H.u[0] = __builtin_amdgcn_perm(a.y, a.x, 0x05040100u);
  H.u[1] = __builtin_amdgcn_perm(a.w, a.z, 0x05040100u);
  H.u[2] = __builtin_amdgcn_perm(b.y, b.x, 0x05040100u);
  H.u[3] = __builtin_amdgcn_perm(b.w, b.z, 0x05040100u);
  L.u[0] = __builtin_amdgcn_perm(a.y, a.x, 0x07060302u);
  L.u[1] = __builtin_amdgcn_perm(a.w, a.z, 0x07060302u);
  L.u[2] = __builtin_amdgcn_perm(b.y, b.x, 0x07060302u);
  L.u[3] = __builtin_amdgcn_perm(b.w, b.z, 0x07060302u);
  *h = H.v; *l = L.v;
}

// ---------------- QKV 1x1 conv ----------------
// v24: v16-proven core + grid-stride zeroing of Oacc/Pc/Lacc (replaces the
// serial hipMemsetAsync dispatch; those buffers are untouched until
// flashgram, which launches after this kernel completes).
__global__ __launch_bounds__(512) void qkv_kernel(
    const float* __restrict__ x, const float* __restrict__ w,
    const float* __restrict__ bias, unsigned short* __restrict__ Qtbf,
    unsigned short* __restrict__ Vbf, unsigned int* __restrict__ Kpk,
    unsigned int* __restrict__ Qtn, float4* __restrict__ zbuf) {
  __shared__ float xs[64][65];  // [channel][pixel]
  __shared__ float qs[64][65];
  int bid = blockIdx.x;
  int b = bid / 100, tile = bid % 100;
  int p0 = tile * 64;
  int t = threadIdx.x;
  // zero accumulator region: 6721536 B = 420096 float4, 204800 threads,
  // coalesced grid-stride (2-3 stores/thread, overlapped with FMA work)
  {
    float4 z = {0.f, 0.f, 0.f, 0.f};
    for (int idx = bid * 512 + t; idx < 420096; idx += 204800) zbuf[idx] = z;
  }
  int i = t & 63;
  int og = __builtin_amdgcn_readfirstlane(t >> 6);  // 0..7
  int p = p0 + i;
  int tp = (p % HW) * HW + p / HW;  // involution transpose
  size_t bc = (size_t)b * CH * NPIX;
  // stage x[b][:, p0..p0+64) -> xs (coalesced: 8 threads/row x 8 floats)
  {
    int cr = t >> 3;         // channel 0..63
    int j0 = (t & 7) * 8;    // pixel chunk 0,8,..,56
    const float* xrow = x + bc + (size_t)cr * NPIX + p0 + j0;
    float4 xa = *(const float4*)&xrow[0];
    float4 xb4 = *(const float4*)&xrow[4];
    xs[cr][j0 + 0] = xa.x; xs[cr][j0 + 1] = xa.y;
    xs[cr][j0 + 2] = xa.z; xs[cr][j0 + 3] = xa.w;
    xs[cr][j0 + 4] = xb4.x; xs[cr][j0 + 5] = xb4.y;
    xs[cr][j0 + 6] = xb4.z; xs[cr][j0 + 7] = xb4.w;
  }
  __syncthreads();
  float xv[64];
#pragma unroll
  for (int c = 0; c < 64; ++c) xv[c] = xs[c][i];
  for (int j = 0; j < 24; j += 4) {
    int o = og * 24 + j;
    const float* wr0 = w + o * 64;
    const float* wr1 = wr0 + 64;
    const float* wr2 = wr0 + 128;
    const float* wr3 = wr0 + 192;
    float a0 = bias[o], a1 = bias[o + 1], a2 = bias[o + 2], a3 = bias[o + 3];
#pragma unroll
    for (int c = 0; c < 64; ++c) {
      float xc = xv[c];
      a0 += wr0[c] * xc;
      a1 += wr1[c] * xc;
      a2 += wr2[c] * xc;
      a3 += wr3[c] * xc;
    }
    float av[4] = {a0, a1, a2, a3};
#pragma unroll
    for (int u = 0; u < 4; ++u) {
      int oo = o + u;
      int cc = oo & 63;
      int kind = oo >> 6;
      float a = av[u];
      if (kind == 0) {
        qs[cc][i] = a;
        Qtn[bc + (size_t)cc * NPIX + tp] = split_pack(a);
      } else if (kind == 1) {
        Kpk[bc + (size_t)cc * NPIX + p] = split_pack(a);
      } else {
        Vbf[bc + (size_t)cc * NPIX + p] = f2bf(a);
      }
    }
  }
  __syncthreads();
  // restage q -> Qtbf rows (row 128B contiguous, scaled by QSCALE)
  int j2 = t >> 3, g = t & 7;  // j2 in [0,64), g in [0,8)
  int pj = p0 + j2;
  int tpj = (pj % HW) * HW + pj / HW;
  unsigned int pk4[4];
#pragma unroll
  for (int q4 = 0; q4 < 4; ++q4) {
    float a0 = qs[g * 8 + q4 * 2][j2] * QSCALE;
    float a1 = qs[g * 8 + q4 * 2 + 1][j2] * QSCALE;
    pk4[q4] = (unsigned int)f2bf(a0) | ((unsigned int)f2bf(a1) << 16);
  }
  unsigned short* dst = Qtbf + ((size_t)b * NPIX + tpj) * 64 + g * 8;
  uint4 w0 = {pk4[0], pk4[1], pk4[2], pk4[3]};
  *(uint4*)&dst[0] = w0;
}

// ---------------- fused flash + gram ----------------
// v23-proven: blocks 0-1199 = flash (R11 body, atomic split-K epilogue),
// 1200-1599 = gram (R4 body). Gram blocks fill flash's idle CU slots.
__global__ __launch_bounds__(256, 4) void flashgram_kernel(
    const unsigned short* __restrict__ Qtbf, const unsigned short* __restrict__ Vbf,
    float* __restrict__ Oacc, float* __restrict__ Lacc,
    const unsigned int* __restrict__ Kpk, const unsigned int* __restrict__ Qtn,
    float* __restrict__ Pc) {
  __shared__ char smem[40960] __attribute__((aligned(128)));
  // flash: Ks [64][64]sh 0..8192; Vs [2] 8192..24576; Pb [2] 24576..40960.
  // gram path never touches smem.

  if (blockIdx.x >= 1200) {
    // ================= gram body (R4-proven, verbatim) =================
    int bid = blockIdx.x - 1200;
    int b = bid / 100, chunk = bid % 100;
    int n0 = chunk * 64;
    int t = threadIdx.x;
    int w = t >> 6, lane = t & 63;
    int quad = lane >> 4, l16 = lane & 15;
    size_t bc = (size_t)b * CH * NPIX;

    f32x4 acc[4];
#pragma unroll
    for (int ct = 0; ct < 4; ++ct) acc[ct] = (f32x4){0.f, 0.f, 0.f, 0.f};

    const unsigned int* kp = Kpk + bc + (size_t)(w * 16 + l16) * NPIX + n0;
    bf16x8 ah[2], al[2];
#pragma unroll
    for (int ks2 = 0; ks2 < 2; ++ks2) {
      uint4 ua = *(const uint4*)&kp[ks2 * 32 + quad * 8];
      uint4 ub = *(const uint4*)&kp[ks2 * 32 + quad * 8 + 4];
      deint(ua, ub, &ah[ks2], &al[ks2]);
    }
#pragma unroll
    for (int ct = 0; ct < 4; ++ct) {
      const unsigned int* qp = Qtn + bc + (size_t)(ct * 16 + l16) * NPIX + n0;
#pragma unroll
      for (int ks2 = 0; ks2 < 2; ++ks2) {
        uint4 va = *(const uint4*)&qp[ks2 * 32 + quad * 8];
        uint4 vb = *(const uint4*)&qp[ks2 * 32 + quad * 8 + 4];
        bf16x8 bh, bl;
        deint(va, vb, &bh, &bl);
        acc[ct] = __builtin_amdgcn_mfma_f32_16x16x32_bf16(ah[ks2], bh, acc[ct], 0, 0, 0);
        acc[ct] = __builtin_amdgcn_mfma_f32_16x16x32_bf16(ah[ks2], bl, acc[ct], 0, 0, 0);
        acc[ct] = __builtin_amdgcn_mfma_f32_16x16x32_bf16(al[ks2], bh, acc[ct], 0, 0, 0);
      }
    }
#pragma unroll
    for (int ct = 0; ct < 4; ++ct)
#pragma unroll
      for (int r = 0; r < 4; ++r)
        atomicAdd(&Pc[((size_t)b * 64 + w * 16 + quad * 4 + r) * 64 + ct * 16 + l16],
                  acc[ct][r]);
    return;
  }

  // ================= flash body (R11-proven core) =================
  int bid = blockIdx.x;
  int b = bid / 300;
  int rem = bid % 300;
  int qt = rem / 3, split = rem % 3;
  int p0 = qt * 64;
  int t = threadIdx.x;
  int w = t >> 6, lane = t & 63;
  int quad = lane >> 4, l16 = lane & 15;
  int sw = l16 & 7;
  size_t bq = (size_t)b * NPIX;
  size_t bC = (size_t)b * CH * NPIX;

  bf16x8 aq[2];
#pragma unroll
  for (int ks = 0; ks < 2; ++ks)
    aq[ks] = *(const bf16x8*)&Qtbf[(bq + p0 + w * 16 + l16) * 64 + ks * 32 + quad * 8];

  f32x4 oacc[4];
#pragma unroll
  for (int ct = 0; ct < 4; ++ct) oacc[ct] = (f32x4){0.f, 0.f, 0.f, 0.f};
  float psum = 0.f;

  const unsigned short* Kb = Qtbf + bq * 64;
  const unsigned short* Vb = Vbf + bC;
  int r0 = t >> 3, s0 = t & 7;  // r0 in [0,32)
  int r1 = r0 + 32;
  int wOff0 = r0 * 64 + ((s0 ^ (r0 & 7)) << 3);  // swizzled LDS dest (halves)
  int wOff1 = r1 * 64 + ((s0 ^ (r1 & 7)) << 3);

  int kt0 = split * 34;
  int niter = (split == 2) ? 32 : 34;

  unsigned short* Ks = (unsigned short*)smem;
  unsigned short* VsB = (unsigned short*)(smem + 8192);   // tile i at +(i&1)*4096 elems
  unsigned short* PbB = (unsigned short*)(smem + 24576);  // iter i at +(i&1)*4096 elems

  uint4 kreg0, kreg1, vreg0, vreg1;
  {  // load + stage tile 0 (A(0)); tile 0 parity = 0
    int n0 = kt0 * 64;
    kreg0 = *(const uint4*)&Kb[(size_t)(n0 + r0) * 64 + s0 * 8];
    vreg0 = *(const uint4*)&Vb[(size_t)r0 * NPIX + n0 + s0 * 8];
    kreg1 = *(const uint4*)&Kb[(size_t)(n0 + r1) * 64 + s0 * 8];
    vreg1 = *(const uint4*)&Vb[(size_t)r1 * NPIX + n0 + s0 * 8];
    *(uint4*)&Ks[wOff0] = kreg0;
    *(uint4*)&Ks[wOff1] = kreg1;
    *(uint4*)&VsB[wOff0] = vreg0;
    *(uint4*)&VsB[wOff1] = vreg1;
  }
  __syncthreads();  // tile 0 staged (this is bar2 of iter 0)

  for (int it = 0; it < niter; ++it) {
    if (it > 0) {
      __syncthreads();  // bar1: B(it-1) done reading Ks and Vs[it&1]
      // A(it): stage tile it from regs (loaded during B(it-1))
      unsigned short* Vn = VsB + ((it & 1) << 12);
      *(uint4*)&Ks[wOff0] = kreg0;
      *(uint4*)&Ks[wOff1] = kreg1;
      *(uint4*)&Vn[wOff0] = vreg0;
      *(uint4*)&Vn[wOff1] = vreg1;
      __syncthreads();  // bar2: tile it visible
    }
    // --- B(it) ---
    // early independent LDS reads of tile it-1 (P is wave-private; V via dbuf)
    bf16x8 pf[2], vf[8];
    if (it > 0) {
      unsigned short* Pprev = PbB + (((it - 1) & 1) << 12) + w * 1024;
      pf[0] = *(const bf16x8*)&Pprev[l16 * 64 + (((0 * 4 + quad) ^ sw) << 3)];
      pf[1] = *(const bf16x8*)&Pprev[l16 * 64 + (((1 * 4 + quad) ^ sw) << 3)];
      unsigned short* Vprev = VsB + (((it - 1) & 1) << 12);
#pragma unroll
      for (int ks = 0; ks < 2; ++ks)
#pragma unroll
        for (int ct = 0; ct < 4; ++ct)
          vf[ks * 4 + ct] = *(const bf16x8*)&Vprev[(ct * 16 + l16) * 64 +
                                                   (((ks * 4 + quad) ^ sw) << 3)];
    }
    // QK(it) on Ks, ESHIFT pre-subtracted via C-in
    f32x4 sc[4];
#pragma unroll
    for (int ct = 0; ct < 4; ++ct)
      sc[ct] = (f32x4){-ESHIFT, -ESHIFT, -ESHIFT, -ESHIFT};
    __builtin_amdgcn_s_setprio(1);
#pragma unroll
    for (int ks = 0; ks < 2; ++ks)
#pragma unroll
      for (int ct = 0; ct < 4; ++ct) {
        bf16x8 bk = *(const bf16x8*)&Ks[(ct * 16 + l16) * 64 +
                                        (((ks * 4 + quad) ^ sw) << 3)];
        sc[ct] = __builtin_amdgcn_mfma_f32_16x16x32_bf16(bk, aq[ks], sc[ct], 0, 0, 0);
      }
    __builtin_amdgcn_s_setprio(0);
    // issue global loads for tile it+1 (consumed at A(it+1))
    if (it + 1 < niter) {
      int n1 = (kt0 + it + 1) * 64;
      kreg0 = *(const uint4*)&Kb[(size_t)(n1 + r0) * 64 + s0 * 8];
      vreg0 = *(const uint4*)&Vb[(size_t)r0 * NPIX + n1 + s0 * 8];
      kreg1 = *(const uint4*)&Kb[(size_t)(n1 + r1) * 64 + s0 * 8];
      vreg1 = *(const uint4*)&Vb[(size_t)r1 * NPIX + n1 + s0 * 8];
    }
    // exp2 + pack -> Pb[it&1] (wave-private region)
    unsigned short* Pw = PbB + ((it & 1) << 12) + w * 1024;
#pragma unroll
    for (int ct = 0; ct < 4; ++ct) {
      float e0 = __builtin_amdgcn_exp2f(sc[ct][0]);
      float e1 = __builtin_amdgcn_exp2f(sc[ct][1]);
      float e2 = __builtin_amdgcn_exp2f(sc[ct][2]);
      float e3 = __builtin_amdgcn_exp2f(sc[ct][3]);
      psum += (e0 + e1) + (e2 + e3);
      unsigned int pk0, pk1;
      asm("v_cvt_pk_bf16_f32 %0, %1, %2" : "=v"(pk0) : "v"(e0), "v"(e1));
      asm("v_cvt_pk_bf16_f32 %0, %1, %2" : "=v"(pk1) : "v"(e2), "v"(e3));
      uint2 pk = {pk0, pk1};
      *(uint2*)&Pw[l16 * 64 +
                   (((2 * ct + (quad >> 1)) ^ sw) << 3) + ((quad & 1) << 2)] = pk;
    }
    // PV(it-1): inputs long since resident -> no stall
    if (it > 0) {
      __builtin_amdgcn_s_setprio(1);
#pragma unroll
      for (int ks = 0; ks < 2; ++ks)
#pragma unroll
        for (int ct = 0; ct < 4; ++ct)
          oacc[ct] = __builtin_amdgcn_mfma_f32_16x16x32_bf16(vf[ks * 4 + ct], pf[ks],
                                                             oacc[ct], 0, 0, 0);
      __builtin_amdgcn_s_setprio(0);
    }
  }
  // epilogue PV(niter-1)
  {
    bf16x8 pf[2], vf[8];
    unsigned short* Pprev = PbB + (((niter - 1) & 1) << 12) + w * 1024;
    pf[0] = *(const bf16x8*)&Pprev[l16 * 64 + (((0 * 4 + quad) ^ sw) << 3)];
    pf[1] = *(const bf16x8*)&Pprev[l16 * 64 + (((1 * 4 + quad) ^ sw) << 3)];
    unsigned short* Vprev = VsB + (((niter - 1) & 1) << 12);
#pragma unroll
    for (int ks = 0; ks < 2; ++ks)
#pragma unroll
      for (int ct = 0; ct < 4; ++ct)
        vf[ks * 4 + ct] = *(const bf16x8*)&Vprev[(ct * 16 + l16) * 64 +
                                                 (((ks * 4 + quad) ^ sw) << 3)];
#pragma unroll
    for (int ks = 0; ks < 2; ++ks)
#pragma unroll
      for (int ct = 0; ct < 4; ++ct)
        oacc[ct] = __builtin_amdgcn_mfma_f32_16x16x32_bf16(vf[ks * 4 + ct], pf[ks],
                                                           oacc[ct], 0, 0, 0);
  }
  // epilogue: atomic split-K reduction into single O/L (zero-init'd per launch)
  float* Op = Oacc + bC;
  int pcol = p0 + w * 16 + l16;
  {
    float s = psum;
    s += __shfl_xor(s, 16, 64);
    s += __shfl_xor(s, 32, 64);
    if (quad == 0) atomicAdd(&Lacc[bq + pcol], s);
  }
#pragma unroll
  for (int ct = 0; ct < 4; ++ct)
#pragma unroll
    for (int r = 0; r < 4; ++r)
      atomicAdd(&Op[(size_t)(ct * 16 + quad * 4 + r) * NPIX + pcol], oacc[ct][r]);
}

// ---------------- finalize ----------------
// v23-proven: single pre-reduced O + single L row; 800-block channel-split.
__global__ __launch_bounds__(256) void finalize_kernel(
    const float* __restrict__ Pc, const unsigned short* __restrict__ Vbf,
    const float* __restrict__ Oacc, const float* __restrict__ Lacc,
    float* __restrict__ out) {
  __shared__ float maT[64 * 32];  // [cp][c_local]
  int bid = blockIdx.x;
  int b = bid / 200;
  int rem = bid % 200;
  int nt = rem >> 1, half = rem & 1;
  int t = threadIdx.x;
  if (t < 32) {
    int c = half * 32 + t;
    const float* row = Pc + ((size_t)b * 64 + c) * 64;
    float v[64];
    float mx = -1e30f;
#pragma unroll
    for (int j = 0; j < 64; ++j) { v[j] = row[j]; mx = fmaxf(mx, v[j]); }
    float s = 0.f;
#pragma unroll
    for (int j = 0; j < 64; ++j) { v[j] = __expf(v[j] - mx); s += v[j]; }
    float inv = 1.f / s;
#pragma unroll
    for (int j = 0; j < 64; ++j) maT[j * 32 + t] = v[j] * inv;
  }
  __syncthreads();
  int lane = t & 63, ct = t >> 6;  // ct in [0,4): 8 channels each
  int n = nt * 64 + lane;
  size_t bc = (size_t)b * CH * NPIX;
  const unsigned short* vb = Vbf + bc + n;
  float acc[8];
#pragma unroll
  for (int j = 0; j < 8; ++j) acc[j] = 0.f;
  for (int cp = 0; cp < 64; ++cp) {
    float vv = bf2f(vb[(size_t)cp * NPIX]);
    const float* m = &maT[cp * 32 + ct * 8];
    f32x4 m0 = *(const f32x4*)&m[0];
    f32x4 m1 = *(const f32x4*)&m[4];
#pragma unroll
    for (int j = 0; j < 4; ++j) {
      acc[j] += m0[j] * vv;
      acc[4 + j] += m1[j] * vv;
    }
  }
  float inv = 1.f / Lacc[(size_t)b * NPIX + n];
  const float* O0 = Oacc + bc;
#pragma unroll
  for (int j = 0; j < 8; ++j) {
    size_t co = (size_t)(half * 32 + ct * 8 + j) * NPIX + n;
    out[bc + co] = acc[j] + O0[co] * inv;
  }
}

extern "C" void kernel_launch(void* const* d_in, const int* in_sizes, int n_in,
                              void* d_out, int out_size, void* d_ws, size_t ws_size,
                              hipStream_t stream) {
  const float* x = (const float*)d_in[0];
  const float* w = (const float*)d_in[1];
  const float* bias = (const float*)d_in[2];
  float* out = (float*)d_out;
  char* ws = (char*)d_ws;
  // layout (bytes):
  unsigned short* Qtbf = (unsigned short*)(ws);           // [0, 3276800)
  unsigned short* Vbf = (unsigned short*)(ws + 3276800);  // [3276800, 6553600)
  unsigned int* Kpk = (unsigned int*)(ws + 6553600);      // [6553600, 13107200)
  unsigned int* Qtn = (unsigned int*)(ws + 13107200);     // [13107200, 19660800)
  float* Oacc = (float*)(ws + 19660800);                  // [19660800, 26214400) single fp32 O
  float* Pc = (float*)(ws + 26214400);                    // [26214400, 26279936)
  float* Lacc = (float*)(ws + 26279936);                  // [26279936, 26382336) single L
  float4* zbuf = (float4*)(ws + 19660800);                // O+Pc+L zero region, 6721536 B

  qkv_kernel<<<400, 512, 0, stream>>>(x, w, bias, Qtbf, Vbf, Kpk, Qtn, zbuf);
  flashgram_kernel<<<1600, 256, 0, stream>>>(Qtbf, Vbf, Oacc, Lacc, Kpk, Qtn, Pc);
  finalize_kernel<<<800, 256, 0, stream>>>(Pc, Vbf, Oacc, Lacc, out);
}